// Round 1
// baseline (89.001 us; speedup 1.0000x reference)
//
#include <hip/hip_runtime.h>
#include <hip/hip_bf16.h>

// Problem: 4-qubit QNN, batch 1M.
// out[b] = psi(x_b)^T * M * psi(x_b), psi = prod_i [cos(x_i/2), sin(x_i/2)],
// M = Re(U^dag Z0 U), U = fixed circuit unitary from weights.
// Wire i maps to bit (3-i) of the flat 16-index (wire 0 = MSB).

#define NQ 4
#define DIM 16

// ---------------- Kernel A: build M (one block, 256 threads) ----------------
__global__ void build_M_kernel(const float* __restrict__ w, float* __restrict__ M) {
    __shared__ float Ur[DIM][DIM + 1];  // [k][col]
    __shared__ float Ui[DIM][DIM + 1];

    const int j = threadIdx.x;

    if (j < DIM) {
        // column j = circuit applied to basis state e_j
        for (int k = 0; k < DIM; ++k) {
            Ur[k][j] = (k == j) ? 1.0f : 0.0f;
            Ui[k][j] = 0.0f;
        }
        for (int layer = 0; layer < 2; ++layer) {
            for (int q = 0; q < NQ; ++q) {
                const float* wq = w + (layer * NQ + q) * 3;
                const int bit = 3 - q;
                const int str = 1 << bit;
                // ---- RX(wq[0]) ----
                {
                    float c, s;
                    sincosf(wq[0] * 0.5f, &s, &c);
                    for (int p = 0; p < 8; ++p) {
                        int k0 = ((p >> bit) << (bit + 1)) | (p & (str - 1));
                        int k1 = k0 | str;
                        float a0r = Ur[k0][j], a0i = Ui[k0][j];
                        float a1r = Ur[k1][j], a1i = Ui[k1][j];
                        // new0 = c*a0 - i s*a1 ; new1 = -i s*a0 + c*a1
                        Ur[k0][j] = c * a0r + s * a1i;
                        Ui[k0][j] = c * a0i - s * a1r;
                        Ur[k1][j] = c * a1r + s * a0i;
                        Ui[k1][j] = c * a1i - s * a0r;
                    }
                }
                // ---- RY(wq[1]) ----
                {
                    float c, s;
                    sincosf(wq[1] * 0.5f, &s, &c);
                    for (int p = 0; p < 8; ++p) {
                        int k0 = ((p >> bit) << (bit + 1)) | (p & (str - 1));
                        int k1 = k0 | str;
                        float a0r = Ur[k0][j], a0i = Ui[k0][j];
                        float a1r = Ur[k1][j], a1i = Ui[k1][j];
                        // new0 = c*a0 - s*a1 ; new1 = s*a0 + c*a1
                        Ur[k0][j] = c * a0r - s * a1r;
                        Ui[k0][j] = c * a0i - s * a1i;
                        Ur[k1][j] = s * a0r + c * a1r;
                        Ui[k1][j] = s * a0i + c * a1i;
                    }
                }
                // ---- RZ(wq[2]) ----
                {
                    float c, s;
                    sincosf(wq[2] * 0.5f, &s, &c);  // phi = t/2
                    for (int p = 0; p < 8; ++p) {
                        int k0 = ((p >> bit) << (bit + 1)) | (p & (str - 1));
                        int k1 = k0 | str;
                        float a0r = Ur[k0][j], a0i = Ui[k0][j];
                        float a1r = Ur[k1][j], a1i = Ui[k1][j];
                        // new0 = e^{-i phi} a0 ; new1 = e^{+i phi} a1
                        Ur[k0][j] = a0r * c + a0i * s;
                        Ui[k0][j] = a0i * c - a0r * s;
                        Ur[k1][j] = a1r * c - a1i * s;
                        Ui[k1][j] = a1i * c + a1r * s;
                    }
                }
            }
            // ---- CNOT ring: (0,1),(1,2),(2,3),(3,0) ----
            const int ctrl[4] = {0, 1, 2, 3};
            const int targ[4] = {1, 2, 3, 0};
            for (int g = 0; g < 4; ++g) {
                int bc = 3 - ctrl[g];
                int bt = 3 - targ[g];
                for (int k = 0; k < DIM; ++k) {
                    if (((k >> bc) & 1) && !((k >> bt) & 1)) {
                        int k2 = k | (1 << bt);
                        float tr = Ur[k][j], ti = Ui[k][j];
                        Ur[k][j] = Ur[k2][j]; Ui[k][j] = Ui[k2][j];
                        Ur[k2][j] = tr;       Ui[k2][j] = ti;
                    }
                }
            }
        }
    }
    __syncthreads();

    // M[a][b] = sum_k z_k * Re( conj(U[k][a]) * U[k][b] ), z_k = (k&8)? -1 : +1
    const int a = j >> 4;
    const int b = j & 15;
    float acc = 0.0f;
    #pragma unroll
    for (int k = 0; k < DIM; ++k) {
        float t = Ur[k][a] * Ur[k][b] + Ui[k][a] * Ui[k][b];
        acc += (k & 8) ? -t : t;
    }
    M[j] = acc;
}

// ---------------- Kernel B: batched quadratic form ----------------
__global__ __launch_bounds__(256) void qnn_eval_kernel(
    const float4* __restrict__ x, const float* __restrict__ M,
    float* __restrict__ out, int n) {
    __shared__ float Ms[256];
    Ms[threadIdx.x] = M[threadIdx.x];
    __syncthreads();

    int i = blockIdx.x * blockDim.x + threadIdx.x;
    if (i >= n) return;

    float4 xv = x[i];
    float c0, s0, c1, s1, c2, s2, c3, s3;
    __sincosf(xv.x * 0.5f, &s0, &c0);
    __sincosf(xv.y * 0.5f, &s1, &c1);
    __sincosf(xv.z * 0.5f, &s2, &c2);
    __sincosf(xv.w * 0.5f, &s3, &c3);

    float p01[4] = {c0 * c1, c0 * s1, s0 * c1, s0 * s1};
    float p23[4] = {c2 * c3, c2 * s3, s2 * c3, s2 * s3};

    float amp[DIM];
    #pragma unroll
    for (int k = 0; k < DIM; ++k) amp[k] = p01[k >> 2] * p23[k & 3];

    float r = 0.0f;
    #pragma unroll
    for (int a = 0; a < DIM; ++a) {
        float t = 0.0f;
        #pragma unroll
        for (int b = 0; b < DIM; ++b) t = fmaf(Ms[a * 16 + b], amp[b], t);
        r = fmaf(amp[a], t, r);
    }
    out[i] = r;
}

// ---------------- launch ----------------
extern "C" void kernel_launch(void* const* d_in, const int* in_sizes, int n_in,
                              void* d_out, int out_size, void* d_ws, size_t ws_size,
                              hipStream_t stream) {
    const float* x = (const float*)d_in[0];
    const float* w = (const float*)d_in[1];
    float* out = (float*)d_out;
    float* M = (float*)d_ws;  // 256 floats

    const int n = in_sizes[0] / 4;  // batch

    build_M_kernel<<<1, 256, 0, stream>>>(w, M);

    const int block = 256;
    const int grid = (n + block - 1) / block;
    qnn_eval_kernel<<<grid, block, 0, stream>>>((const float4*)x, M, out, n);
}

// Round 3
// 69.491 us; speedup vs baseline: 1.2808x; 1.2808x over previous
//
#include <hip/hip_runtime.h>
#include <hip/hip_bf16.h>

// 4-qubit QNN, batch 1M.
// out[b] = psi^T M psi, psi = prod_i [cos(x_i/2), sin(x_i/2)] (wire i = bit 3-i),
// M = Re(U^dag Z0 U). Expanded per qubit: c^2=(1+C)/2, cs=S/2, s^2=(1-C)/2
// (C=cos x, S=sin x)  =>  out = sum_{g in {1,C,S}^4} K[g] * prod basis.
// Kernel A builds U (register+shuffle sim), M, then the 81 K coefficients.
// Kernel B evaluates the 81-term tensor polynomial, 4 samples/thread.

#define VEC 4

// ---------------- Kernel A: one block, 256 threads ----------------
__global__ void build_K_kernel(const float* __restrict__ w, float* __restrict__ K) {
    __shared__ float Ur[16][17], Ui[16][17];
    __shared__ float Msh[256];

    const int t = threadIdx.x;
    const int j = t >> 4;   // column (basis input)
    const int k = t & 15;   // row (amplitude index)

    float ur = (k == j) ? 1.0f : 0.0f;
    float ui = 0.0f;

    #pragma unroll
    for (int layer = 0; layer < 2; ++layer) {
        #pragma unroll
        for (int q = 0; q < 4; ++q) {
            const int bit = 3 - q;          // wire q acts on bit (3-q)
            const int str = 1 << bit;
            const int kb = (k >> bit) & 1;
            float c, s, pr, pi, nr, ni;
            // ---- RX ----
            __sincosf(w[(layer * 4 + q) * 3 + 0] * 0.5f, &s, &c);
            pr = __shfl_xor(ur, str);
            pi = __shfl_xor(ui, str);
            nr = c * ur + s * pi;           // new = c*a - i*s*partner
            ni = c * ui - s * pr;
            ur = nr; ui = ni;
            // ---- RY ----
            __sincosf(w[(layer * 4 + q) * 3 + 1] * 0.5f, &s, &c);
            pr = __shfl_xor(ur, str);
            pi = __shfl_xor(ui, str);
            {
                const float sg = kb ? s : -s;   // new0 = c a0 - s a1 ; new1 = s a0 + c a1
                nr = c * ur + sg * pr;
                ni = c * ui + sg * pi;
            }
            ur = nr; ui = ni;
            // ---- RZ ----
            __sincosf(w[(layer * 4 + q) * 3 + 2] * 0.5f, &s, &c);
            {
                const float sz = kb ? s : -s;   // new = e^{-+i phi} a
                nr = c * ur - sz * ui;
                ni = c * ui + sz * ur;
            }
            ur = nr; ui = ni;
        }
        // ---- CNOT ring (0,1),(1,2),(2,3),(3,0) ----
        #pragma unroll
        for (int g = 0; g < 4; ++g) {
            const int cw = g;
            const int tw = (g + 1) & 3;
            const int bc = 3 - cw, bt = 3 - tw;
            const float pr = __shfl_xor(ur, 1 << bt);
            const float pi = __shfl_xor(ui, 1 << bt);
            const bool ctl = (k >> bc) & 1;
            ur = ctl ? pr : ur;
            ui = ctl ? pi : ui;
        }
    }

    Ur[k][j] = ur;
    Ui[k][j] = ui;
    __syncthreads();

    // M[a][b] = sum_k z_k Re(conj(U[k][a]) U[k][b]), z_k = (k&8) ? -1 : +1
    {
        const int a = t >> 4, b = t & 15;
        float acc = 0.0f;
        #pragma unroll
        for (int kk = 0; kk < 16; ++kk) {
            const float v2 = Ur[kk][a] * Ur[kk][b] + Ui[kk][a] * Ui[kk][b];
            acc += (kk & 8) ? -v2 : v2;
        }
        Msh[t] = acc;
    }
    __syncthreads();

    // K[g] for g in {0,1,2}^4 (digit d0 <-> bit3/wire0 ... d3 <-> bit0/wire3):
    // per qubit: g=0 -> diag +; g=1 -> diag, sign - if bit set; g=2 -> off-diag.
    // Each K[g] = (1/16) * sum over 16 signed M entries.
    if (t < 81) {
        const int d0 = t / 27, d1 = (t / 9) % 3, d2 = (t / 3) % 3, d3 = t % 3;
        const int gd[4] = {d3, d2, d1, d0};  // gd[bit p]
        float sum = 0.0f;
        #pragma unroll
        for (int m = 0; m < 16; ++m) {
            int a2 = 0, b2 = 0;
            float sign = 1.0f;
            #pragma unroll
            for (int p = 0; p < 4; ++p) {
                const int cp = (m >> p) & 1;
                if (gd[p] == 2) { a2 |= cp << p; b2 |= (1 - cp) << p; }
                else {
                    a2 |= cp << p; b2 |= cp << p;
                    if (gd[p] == 1 && cp) sign = -sign;
                }
            }
            sum += sign * Msh[a2 * 16 + b2];
        }
        K[t] = sum * 0.0625f;
    }
}

// ---------------- Kernel B: 81-term tensor polynomial ----------------
__global__ __launch_bounds__(256) void qnn_eval_kernel(
    const float4* __restrict__ x, const float* __restrict__ K,
    float* __restrict__ out, int n) {
    __shared__ float Ks[81];
    if (threadIdx.x < 81) Ks[threadIdx.x] = K[threadIdx.x];
    __syncthreads();

    const int gid = blockIdx.x * blockDim.x + threadIdx.x;
    const int stride = gridDim.x * blockDim.x;

    for (int i0 = gid; i0 < n; i0 += stride * VEC) {
        int idx[VEC];
        bool ok[VEC];
        float C[VEC][4], S[VEC][4];
        #pragma unroll
        for (int v = 0; v < VEC; ++v) {
            const int ii = i0 + v * stride;
            ok[v] = ii < n;
            idx[v] = ok[v] ? ii : (n - 1);
            const float4 xv = x[idx[v]];
            __sincosf(xv.x, &S[v][0], &C[v][0]);
            __sincosf(xv.y, &S[v][1], &C[v][1]);
            __sincosf(xv.z, &S[v][2], &C[v][2]);
            __sincosf(xv.w, &S[v][3], &C[v][3]);
        }

        float r[VEC];
        #pragma unroll
        for (int d0 = 0; d0 < 3; ++d0) {
            float a1[VEC];
            #pragma unroll
            for (int d1 = 0; d1 < 3; ++d1) {
                float a2[VEC];
                #pragma unroll
                for (int d2 = 0; d2 < 3; ++d2) {
                    const int base = ((d0 * 3 + d1) * 3 + d2) * 3;
                    const float k0 = Ks[base], k1 = Ks[base + 1], k2 = Ks[base + 2];
                    #pragma unroll
                    for (int v = 0; v < VEC; ++v) {
                        const float tt = fmaf(k2, S[v][3], fmaf(k1, C[v][3], k0));
                        if (d2 == 0) a2[v] = tt;
                        else a2[v] = fmaf(tt, (d2 == 1) ? C[v][2] : S[v][2], a2[v]);
                    }
                }
                #pragma unroll
                for (int v = 0; v < VEC; ++v) {
                    if (d1 == 0) a1[v] = a2[v];
                    else a1[v] = fmaf(a2[v], (d1 == 1) ? C[v][1] : S[v][1], a1[v]);
                }
            }
            #pragma unroll
            for (int v = 0; v < VEC; ++v) {
                if (d0 == 0) r[v] = a1[v];
                else r[v] = fmaf(a1[v], (d0 == 1) ? C[v][0] : S[v][0], r[v]);
            }
        }

        #pragma unroll
        for (int v = 0; v < VEC; ++v)
            if (ok[v]) out[idx[v]] = r[v];
    }
}

// ---------------- launch ----------------
extern "C" void kernel_launch(void* const* d_in, const int* in_sizes, int n_in,
                              void* d_out, int out_size, void* d_ws, size_t ws_size,
                              hipStream_t stream) {
    const float* x = (const float*)d_in[0];
    const float* w = (const float*)d_in[1];
    float* out = (float*)d_out;
    float* K = (float*)d_ws;  // 81 floats

    const int n = in_sizes[0] / 4;  // batch

    build_K_kernel<<<1, 256, 0, stream>>>(w, K);

    const int block = 256;
    const int per_block = block * VEC;
    int grid = (n + per_block - 1) / per_block;
    if (grid < 1) grid = 1;
    qnn_eval_kernel<<<grid, block, 0, stream>>>((const float4*)x, K, out, n);
}